// Round 2
// baseline (1918.191 us; speedup 1.0000x reference)
//
#include <hip/hip_runtime.h>

#define N_NODES 100000
#define N_EDGES 1600000
#define DIM 128
#define NCLS 64
#define NG 128
#define BN_EPS 1e-5f

// ---------------- degree histogram ----------------
__global__ void k_hist(const int* __restrict__ dst, int* __restrict__ cnt) {
    int e = blockIdx.x * 256 + threadIdx.x;
    if (e < N_EDGES) atomicAdd(&cnt[dst[e]], 1);
}

// ---------------- exclusive scan (3 kernels) ----------------
__global__ void k_scan1(const int* __restrict__ cnt, int* __restrict__ rowptr,
                        int* __restrict__ bsums) {
    __shared__ int sd[1024];
    int tid = threadIdx.x;
    int i = blockIdx.x * 1024 + tid;
    int v = (i < N_NODES) ? cnt[i] : 0;
    sd[tid] = v;
    __syncthreads();
    for (int off = 1; off < 1024; off <<= 1) {
        int t2 = (tid >= off) ? sd[tid - off] : 0;
        __syncthreads();
        sd[tid] += t2;
        __syncthreads();
    }
    if (i < N_NODES) rowptr[i] = sd[tid] - v;   // exclusive within block
    if (tid == 1023) bsums[blockIdx.x] = sd[tid];
}

__global__ void k_scan2(int* __restrict__ bsums, int nb) {  // nb <= 128
    __shared__ int sd[128];
    int t = threadIdx.x;
    int v = (t < nb) ? bsums[t] : 0;
    sd[t] = v;
    __syncthreads();
    for (int off = 1; off < 128; off <<= 1) {
        int u = (t >= off) ? sd[t - off] : 0;
        __syncthreads();
        sd[t] += u;
        __syncthreads();
    }
    if (t < nb) bsums[t] = sd[t] - v;   // exclusive
}

__global__ void k_scan3(int* __restrict__ rowptr, const int* __restrict__ bsums,
                        int* __restrict__ wcur) {
    int i = blockIdx.x * 1024 + threadIdx.x;
    if (i < N_NODES) {
        int v = rowptr[i] + bsums[blockIdx.x];
        rowptr[i] = v;
        wcur[i] = v;
    }
    if (i == N_NODES - 1) rowptr[N_NODES] = N_EDGES;
}

// ---------------- bucket edges by dst ----------------
__global__ void k_scatter(const int* __restrict__ src, const int* __restrict__ dst,
                          int* __restrict__ wcur, int2* __restrict__ esort) {
    int e = blockIdx.x * 256 + threadIdx.x;
    if (e < N_EDGES) {
        int d = dst[e];
        int p = atomicAdd(&wcur[d], 1);
        esort[p] = make_int2(e, src[e]);
    }
}

// ---------------- gather-aggregate: one wave per node, 2 edges/half-wave ----
// agg[n] = mean over incoming edges of relu(bn?(F[src]) + xe[e])
__global__ __launch_bounds__(256) void k_agg(
        const float* __restrict__ F, const float* __restrict__ xe,
        const int* __restrict__ rowptr, const int2* __restrict__ esort,
        float* __restrict__ agg, const float* __restrict__ bnsc, int applyBN) {
    int wid = (blockIdx.x * blockDim.x + threadIdx.x) >> 6;  // node id
    int lane = threadIdx.x & 63;
    if (wid >= N_NODES) return;
    int half = lane >> 5;      // which edge of the pair
    int l = lane & 31;         // float4 slot: dims 4l..4l+3
    int p0 = rowptr[wid], p1 = rowptr[wid + 1];
    if (p0 == p1) {
        if (half == 0) {
            float4 z = make_float4(0.f, 0.f, 0.f, 0.f);
            *reinterpret_cast<float4*>(&agg[(size_t)wid * DIM + l * 4]) = z;
        }
        return;
    }
    float4 sc, sh;
    if (applyBN) {
        sc = *reinterpret_cast<const float4*>(&bnsc[l * 4]);
        sh = *reinterpret_cast<const float4*>(&bnsc[DIM + l * 4]);
    }
    float4 acc = make_float4(0.f, 0.f, 0.f, 0.f);
    for (int p = p0; p < p1; p += 4) {
        int q0 = p + half;
        int q1 = p + 2 + half;
        int2 e0 = esort[min(q0, p1 - 1)];
        int2 e1 = esort[min(q1, p1 - 1)];
        float4 a0 = *reinterpret_cast<const float4*>(&F[(size_t)e0.y * DIM + l * 4]);
        float4 b0 = *reinterpret_cast<const float4*>(&xe[(size_t)e0.x * DIM + l * 4]);
        float4 a1 = *reinterpret_cast<const float4*>(&F[(size_t)e1.y * DIM + l * 4]);
        float4 b1 = *reinterpret_cast<const float4*>(&xe[(size_t)e1.x * DIM + l * 4]);
        if (applyBN) {
            a0.x = fmaxf(a0.x * sc.x + sh.x, 0.f); a0.y = fmaxf(a0.y * sc.y + sh.y, 0.f);
            a0.z = fmaxf(a0.z * sc.z + sh.z, 0.f); a0.w = fmaxf(a0.w * sc.w + sh.w, 0.f);
            a1.x = fmaxf(a1.x * sc.x + sh.x, 0.f); a1.y = fmaxf(a1.y * sc.y + sh.y, 0.f);
            a1.z = fmaxf(a1.z * sc.z + sh.z, 0.f); a1.w = fmaxf(a1.w * sc.w + sh.w, 0.f);
        }
        if (q0 < p1) {
            acc.x += fmaxf(a0.x + b0.x, 0.f);
            acc.y += fmaxf(a0.y + b0.y, 0.f);
            acc.z += fmaxf(a0.z + b0.z, 0.f);
            acc.w += fmaxf(a0.w + b0.w, 0.f);
        }
        if (q1 < p1) {
            acc.x += fmaxf(a1.x + b1.x, 0.f);
            acc.y += fmaxf(a1.y + b1.y, 0.f);
            acc.z += fmaxf(a1.z + b1.z, 0.f);
            acc.w += fmaxf(a1.w + b1.w, 0.f);
        }
    }
    acc.x += __shfl_xor(acc.x, 32);
    acc.y += __shfl_xor(acc.y, 32);
    acc.z += __shfl_xor(acc.z, 32);
    acc.w += __shfl_xor(acc.w, 32);
    if (half == 0) {
        float s = 1.f / (float)(p1 - p0);
        acc.x *= s; acc.y *= s; acc.z *= s; acc.w *= s;
        *reinterpret_cast<float4*>(&agg[(size_t)wid * DIM + l * 4]) = acc;
    }
}

// ---------------- fused dual GEMM: OUT = A@W1^T + bn?(B)@W2^T + bias (+BN stats)
__global__ __launch_bounds__(256, 3) void k_gemm2(
        const float* __restrict__ A, const float* __restrict__ B,
        const float* __restrict__ W1, const float* __restrict__ W2,
        const float* __restrict__ bias, float* __restrict__ OUT,
        float* __restrict__ bnacc, const float* __restrict__ bnsc,
        int doBN, int bnB) {
    __shared__ float As[64][34];
    __shared__ float Bs[64][34];
    __shared__ float W1s[128][34];
    __shared__ float W2s[128][34];
    int t = threadIdx.x;
    int n0 = blockIdx.x * 64;
    int tn = t >> 4;   // 0..15  node group (4 nodes each)
    int td = t & 15;   // 0..15  dim group  (dims d = td + 16*j)
    float acc[4][8];
#pragma unroll
    for (int i = 0; i < 4; ++i)
#pragma unroll
        for (int j = 0; j < 8; ++j) acc[i][j] = 0.f;

    int lr = t >> 3;          // 0..31
    int lc = (t & 7) * 4;     // 0..28

    for (int kc = 0; kc < 4; ++kc) {
        int kb = kc * 32;
        __syncthreads();
#pragma unroll
        for (int h = 0; h < 2; ++h) {
            int r = lr + h * 32;
            int n = n0 + r; if (n > N_NODES - 1) n = N_NODES - 1;
            *reinterpret_cast<float4*>(&As[r][lc]) =
                *reinterpret_cast<const float4*>(&A[(size_t)n * DIM + kb + lc]);
            float4 v = *reinterpret_cast<const float4*>(&B[(size_t)n * DIM + kb + lc]);
            if (bnB) {
                float4 sc = *reinterpret_cast<const float4*>(&bnsc[kb + lc]);
                float4 sh = *reinterpret_cast<const float4*>(&bnsc[DIM + kb + lc]);
                v.x = fmaxf(v.x * sc.x + sh.x, 0.f);
                v.y = fmaxf(v.y * sc.y + sh.y, 0.f);
                v.z = fmaxf(v.z * sc.z + sh.z, 0.f);
                v.w = fmaxf(v.w * sc.w + sh.w, 0.f);
            }
            *reinterpret_cast<float4*>(&Bs[r][lc]) = v;
        }
#pragma unroll
        for (int h = 0; h < 4; ++h) {
            int r = lr + h * 32;
            *reinterpret_cast<float4*>(&W1s[r][lc]) =
                *reinterpret_cast<const float4*>(&W1[(size_t)r * DIM + kb + lc]);
            *reinterpret_cast<float4*>(&W2s[r][lc]) =
                *reinterpret_cast<const float4*>(&W2[(size_t)r * DIM + kb + lc]);
        }
        __syncthreads();
#pragma unroll
        for (int kk = 0; kk < 8; ++kk) {
            float4 a[4], b[4], w1[8], w2[8];
#pragma unroll
            for (int i = 0; i < 4; ++i) {
                a[i] = *reinterpret_cast<const float4*>(&As[tn * 4 + i][kk * 4]);
                b[i] = *reinterpret_cast<const float4*>(&Bs[tn * 4 + i][kk * 4]);
            }
#pragma unroll
            for (int j = 0; j < 8; ++j) {
                w1[j] = *reinterpret_cast<const float4*>(&W1s[td + 16 * j][kk * 4]);
                w2[j] = *reinterpret_cast<const float4*>(&W2s[td + 16 * j][kk * 4]);
            }
#pragma unroll
            for (int i = 0; i < 4; ++i)
#pragma unroll
                for (int j = 0; j < 8; ++j) {
                    acc[i][j] += a[i].x * w1[j].x + a[i].y * w1[j].y
                               + a[i].z * w1[j].z + a[i].w * w1[j].w
                               + b[i].x * w2[j].x + b[i].y * w2[j].y
                               + b[i].z * w2[j].z + b[i].w * w2[j].w;
                }
        }
    }

    float bj[8];
#pragma unroll
    for (int j = 0; j < 8; ++j) bj[j] = bias[td + 16 * j];
    float p1s[8], p2s[8];
#pragma unroll
    for (int j = 0; j < 8; ++j) { p1s[j] = 0.f; p2s[j] = 0.f; }
#pragma unroll
    for (int i = 0; i < 4; ++i) {
        int n = n0 + tn * 4 + i;
        if (n < N_NODES) {
#pragma unroll
            for (int j = 0; j < 8; ++j) {
                float h = acc[i][j] + bj[j];
                OUT[(size_t)n * DIM + td + 16 * j] = h;
                p1s[j] += h;
                p2s[j] += h * h;
            }
        }
    }
    if (doBN) {
        __syncthreads();
        float* red1 = &As[0][0];   // 16*128 = 2048 <= 2176 floats
        float* red2 = &Bs[0][0];
#pragma unroll
        for (int j = 0; j < 8; ++j) {
            red1[tn * 128 + td + 16 * j] = p1s[j];
            red2[tn * 128 + td + 16 * j] = p2s[j];
        }
        __syncthreads();
        if (t < 128) {
            float s1 = 0.f, s2 = 0.f;
#pragma unroll
            for (int g = 0; g < 16; ++g) { s1 += red1[g * 128 + t]; s2 += red2[g * 128 + t]; }
            atomicAdd(&bnacc[t], s1);
            atomicAdd(&bnacc[128 + t], s2);
        }
    }
}

// ---------------- BN finalize: scale/shift vector ----------------
__global__ void k_bnfinal(const float* __restrict__ bnacc, const float* __restrict__ gamma,
                          const float* __restrict__ beta, float* __restrict__ bnsc) {
    int d = threadIdx.x;
    if (d < DIM) {
        float mu = bnacc[d] / (float)N_NODES;
        float var = bnacc[128 + d] / (float)N_NODES - mu * mu;
        float rstd = rsqrtf(var + BN_EPS);
        float sc = gamma[d] * rstd;
        bnsc[d] = sc;
        bnsc[128 + d] = beta[d] - mu * sc;
    }
}

// ---------------- graph mean pool (batch is sorted), 4 slices ----------------
__global__ void k_pool(const float* __restrict__ H1, const int* __restrict__ batch,
                       float* __restrict__ gout) {
    __shared__ float red[4][128];
    int g = blockIdx.x;
    int t = threadIdx.x;       // 512
    int d = t & 127;
    int sl = t >> 7;           // 0..3
    int lo = 0, hi = N_NODES;
    while (lo < hi) { int m = (lo + hi) >> 1; if (batch[m] < g) lo = m + 1; else hi = m; }
    int s = lo;
    lo = 0; hi = N_NODES;
    while (lo < hi) { int m = (lo + hi) >> 1; if (batch[m] < g + 1) lo = m + 1; else hi = m; }
    int e = lo;
    float sum = 0.f;
    for (int n = s + sl; n < e; n += 4) sum += H1[(size_t)n * DIM + d];
    red[sl][d] = sum;
    __syncthreads();
    if (t < 128) {
        float tot = red[0][d] + red[1][d] + red[2][d] + red[3][d];
        gout[g * DIM + d] = tot / (float)max(e - s, 1);
    }
}

// ---------------- projection: OUT = relu(H1) @ Wp^T + bp ----------------
__global__ __launch_bounds__(256) void k_proj(const float* __restrict__ H1,
                                              const float* __restrict__ Wp,
                                              const float* __restrict__ bp,
                                              float* __restrict__ OUT) {
    __shared__ float As[64][34];
    __shared__ float Ws[64][34];
    int t = threadIdx.x;
    int n0 = blockIdx.x * 64;
    int tn = t >> 4;  // 0..15
    int tc = t & 15;  // 0..15, c = tc + 16*j
    float acc[4][4];
#pragma unroll
    for (int i = 0; i < 4; ++i)
#pragma unroll
        for (int j = 0; j < 4; ++j) acc[i][j] = 0.f;
    int lr = t >> 3;
    int lc = (t & 7) * 4;
    for (int kc = 0; kc < 4; ++kc) {
        int kb = kc * 32;
        __syncthreads();
#pragma unroll
        for (int h = 0; h < 2; ++h) {
            int r = lr + h * 32;
            int n = n0 + r; if (n > N_NODES - 1) n = N_NODES - 1;
            float4 v = *reinterpret_cast<const float4*>(&H1[(size_t)n * DIM + kb + lc]);
            v.x = fmaxf(v.x, 0.f); v.y = fmaxf(v.y, 0.f);
            v.z = fmaxf(v.z, 0.f); v.w = fmaxf(v.w, 0.f);
            *reinterpret_cast<float4*>(&As[r][lc]) = v;
            *reinterpret_cast<float4*>(&Ws[r][lc]) =
                *reinterpret_cast<const float4*>(&Wp[(size_t)r * DIM + kb + lc]);
        }
        __syncthreads();
#pragma unroll
        for (int kk = 0; kk < 8; ++kk) {
            float4 a[4], w[4];
#pragma unroll
            for (int i = 0; i < 4; ++i)
                a[i] = *reinterpret_cast<const float4*>(&As[tn * 4 + i][kk * 4]);
#pragma unroll
            for (int j = 0; j < 4; ++j)
                w[j] = *reinterpret_cast<const float4*>(&Ws[tc + 16 * j][kk * 4]);
#pragma unroll
            for (int i = 0; i < 4; ++i)
#pragma unroll
                for (int j = 0; j < 4; ++j)
                    acc[i][j] += a[i].x * w[j].x + a[i].y * w[j].y
                               + a[i].z * w[j].z + a[i].w * w[j].w;
        }
    }
    float bj[4];
#pragma unroll
    for (int j = 0; j < 4; ++j) bj[j] = bp[tc + 16 * j];
#pragma unroll
    for (int i = 0; i < 4; ++i) {
        int n = n0 + tn * 4 + i;
        if (n < N_NODES) {
#pragma unroll
            for (int j = 0; j < 4; ++j)
                OUT[(size_t)n * NCLS + tc + 16 * j] = acc[i][j] + bj[j];
        }
    }
}

extern "C" void kernel_launch(void* const* d_in, const int* in_sizes, int n_in,
                              void* d_out, int out_size, void* d_ws, size_t ws_size,
                              hipStream_t stream) {
    (void)in_sizes; (void)n_in; (void)out_size; (void)ws_size;
    const float* x     = (const float*)d_in[0];
    const float* xe    = (const float*)d_in[1];
    const int*   eidx  = (const int*)d_in[2];
    const int*   batch = (const int*)d_in[3];
    const float* Wl0   = (const float*)d_in[4];
    const float* bl0   = (const float*)d_in[5];
    const float* Wr0   = (const float*)d_in[6];
    const float* Wl1   = (const float*)d_in[7];
    const float* bl1   = (const float*)d_in[8];
    const float* Wr1   = (const float*)d_in[9];
    const float* gamma0 = (const float*)d_in[10];
    const float* beta0  = (const float*)d_in[11];
    const float* Wp    = (const float*)d_in[12];
    const float* bp    = (const float*)d_in[13];
    const int* srcp = eidx;
    const int* dstp = eidx + N_EDGES;

    char* ws = (char*)d_ws;
    size_t off = 0;
    auto carve = [&](size_t bytes) {
        void* p = ws + off;
        off = (off + bytes + 255) & ~(size_t)255;
        return p;
    };
    int*   cnt    = (int*)carve((size_t)N_NODES * 4);
    int*   rowptr = (int*)carve((size_t)(N_NODES + 1) * 4);
    int*   wcur   = (int*)carve((size_t)N_NODES * 4);
    int*   bsums  = (int*)carve(128 * 4);
    float* bnacc  = (float*)carve(256 * 4);
    float* bnsc   = (float*)carve(256 * 4);
    int2*  esort  = (int2*)carve((size_t)N_EDGES * 8);
    float* AGG    = (float*)carve((size_t)N_NODES * DIM * 4);
    float* H      = (float*)carve((size_t)N_NODES * DIM * 4);
    float* H1     = (float*)carve((size_t)N_NODES * DIM * 4);

    float* out_h = (float*)d_out;
    float* out_g = out_h + (size_t)N_NODES * NCLS;

    hipMemsetAsync(cnt, 0, (size_t)N_NODES * 4, stream);
    hipMemsetAsync(bnacc, 0, 256 * 4, stream);

    int nb = (N_NODES + 1023) / 1024;  // 98
    k_hist<<<(N_EDGES + 255) / 256, 256, 0, stream>>>(dstp, cnt);
    k_scan1<<<nb, 1024, 0, stream>>>(cnt, rowptr, bsums);
    k_scan2<<<1, 128, 0, stream>>>(bsums, nb);
    k_scan3<<<nb, 1024, 0, stream>>>(rowptr, bsums, wcur);
    k_scatter<<<(N_EDGES + 255) / 256, 256, 0, stream>>>(srcp, dstp, wcur, esort);

    // layer 0: agg -> dual GEMM (+BN stats)
    k_agg<<<(N_NODES * 64 + 255) / 256, 256, 0, stream>>>(x, xe, rowptr, esort, AGG,
                                                          bnsc, 0);
    k_gemm2<<<(N_NODES + 63) / 64, 256, 0, stream>>>(AGG, x, Wl0, Wr0, bl0, H,
                                                     bnacc, bnsc, 1, 0);
    k_bnfinal<<<1, 128, 0, stream>>>(bnacc, gamma0, beta0, bnsc);

    // layer 1: agg (BN fused on gathered H) -> dual GEMM (BN fused on B side)
    k_agg<<<(N_NODES * 64 + 255) / 256, 256, 0, stream>>>(H, xe, rowptr, esort, AGG,
                                                          bnsc, 1);
    k_gemm2<<<(N_NODES + 63) / 64, 256, 0, stream>>>(AGG, H, Wl1, Wr1, bl1, H1,
                                                     bnacc, bnsc, 0, 1);

    // readout
    k_pool<<<NG, 512, 0, stream>>>(H1, batch, out_g);
    k_proj<<<(N_NODES + 63) / 64, 256, 0, stream>>>(H1, Wp, bp, out_h);
}

// Round 4
// 1019.497 us; speedup vs baseline: 1.8815x; 1.8815x over previous
//
#include <hip/hip_runtime.h>

#define N_NODES 100000
#define N_EDGES 1600000
#define DIM 128
#define NCLS 64
#define NG 128
#define BN_EPS 1e-5f

typedef __attribute__((ext_vector_type(8))) short s16x8;
typedef __attribute__((ext_vector_type(4))) float f32x4;
#define MFMA_BF16 __builtin_amdgcn_mfma_f32_16x16x32_bf16

// split 8 f32 into bf16 hi + bf16 lo (truncation; dropped lo*lo term ~2^-18 rel)
__device__ __forceinline__ void f2hl8(float4 v0, float4 v1, s16x8& h8, s16x8& l8) {
    float vv[8] = {v0.x, v0.y, v0.z, v0.w, v1.x, v1.y, v1.z, v1.w};
#pragma unroll
    for (int i = 0; i < 8; ++i) {
        unsigned u = __float_as_uint(vv[i]);
        short h = (short)(u >> 16);
        float r = vv[i] - __uint_as_float(u & 0xFFFF0000u);
        short l = (short)(__float_as_uint(r) >> 16);
        h8[i] = h;
        l8[i] = l;
    }
}

// ---------------- degree histogram ----------------
__global__ void k_hist(const int* __restrict__ dst, int* __restrict__ cnt) {
    int e = blockIdx.x * 256 + threadIdx.x;
    if (e < N_EDGES) atomicAdd(&cnt[dst[e]], 1);
}

// ---------------- exclusive scan (3 kernels) ----------------
__global__ void k_scan1(const int* __restrict__ cnt, int* __restrict__ rowptr,
                        int* __restrict__ bsums) {
    __shared__ int sd[1024];
    int tid = threadIdx.x;
    int i = blockIdx.x * 1024 + tid;
    int v = (i < N_NODES) ? cnt[i] : 0;
    sd[tid] = v;
    __syncthreads();
    for (int off = 1; off < 1024; off <<= 1) {
        int t2 = (tid >= off) ? sd[tid - off] : 0;
        __syncthreads();
        sd[tid] += t2;
        __syncthreads();
    }
    if (i < N_NODES) rowptr[i] = sd[tid] - v;
    if (tid == 1023) bsums[blockIdx.x] = sd[tid];
}

__global__ void k_scan2(int* __restrict__ bsums, int nb) {
    __shared__ int sd[128];
    int t = threadIdx.x;
    int v = (t < nb) ? bsums[t] : 0;
    sd[t] = v;
    __syncthreads();
    for (int off = 1; off < 128; off <<= 1) {
        int u = (t >= off) ? sd[t - off] : 0;
        __syncthreads();
        sd[t] += u;
        __syncthreads();
    }
    if (t < nb) bsums[t] = sd[t] - v;
}

__global__ void k_scan3(int* __restrict__ rowptr, const int* __restrict__ bsums,
                        int* __restrict__ wcur) {
    int i = blockIdx.x * 1024 + threadIdx.x;
    if (i < N_NODES) {
        int v = rowptr[i] + bsums[blockIdx.x];
        rowptr[i] = v;
        wcur[i] = v;
    }
    if (i == N_NODES - 1) rowptr[N_NODES] = N_EDGES;
}

// ---------------- bucket edges by dst ----------------
__global__ void k_scatter(const int* __restrict__ src, const int* __restrict__ dst,
                          int* __restrict__ wcur, int2* __restrict__ esort) {
    int e = blockIdx.x * 256 + threadIdx.x;
    if (e < N_EDGES) {
        int d = dst[e];
        int p = atomicAdd(&wcur[d], 1);
        esort[p] = make_int2(e, src[e]);
    }
}

// ---------------- gather-aggregate: one wave per node, 2 edges/half-wave ----
__global__ __launch_bounds__(256) void k_agg(
        const float* __restrict__ F, const float* __restrict__ xe,
        const int* __restrict__ rowptr, const int2* __restrict__ esort,
        float* __restrict__ agg, const float* __restrict__ bnsc, int applyBN) {
    int wid = (blockIdx.x * blockDim.x + threadIdx.x) >> 6;
    int lane = threadIdx.x & 63;
    if (wid >= N_NODES) return;
    int half = lane >> 5;
    int l = lane & 31;
    int p0 = rowptr[wid], p1 = rowptr[wid + 1];
    if (p0 == p1) {
        if (half == 0) {
            float4 z = make_float4(0.f, 0.f, 0.f, 0.f);
            *reinterpret_cast<float4*>(&agg[(size_t)wid * DIM + l * 4]) = z;
        }
        return;
    }
    float4 sc, sh;
    if (applyBN) {
        sc = *reinterpret_cast<const float4*>(&bnsc[l * 4]);
        sh = *reinterpret_cast<const float4*>(&bnsc[DIM + l * 4]);
    }
    float4 acc = make_float4(0.f, 0.f, 0.f, 0.f);
    for (int p = p0; p < p1; p += 4) {
        int q0 = p + half;
        int q1 = p + 2 + half;
        int2 e0 = esort[min(q0, p1 - 1)];
        int2 e1 = esort[min(q1, p1 - 1)];
        float4 a0 = *reinterpret_cast<const float4*>(&F[(size_t)e0.y * DIM + l * 4]);
        float4 b0 = *reinterpret_cast<const float4*>(&xe[(size_t)e0.x * DIM + l * 4]);
        float4 a1 = *reinterpret_cast<const float4*>(&F[(size_t)e1.y * DIM + l * 4]);
        float4 b1 = *reinterpret_cast<const float4*>(&xe[(size_t)e1.x * DIM + l * 4]);
        if (applyBN) {
            a0.x = fmaxf(a0.x * sc.x + sh.x, 0.f); a0.y = fmaxf(a0.y * sc.y + sh.y, 0.f);
            a0.z = fmaxf(a0.z * sc.z + sh.z, 0.f); a0.w = fmaxf(a0.w * sc.w + sh.w, 0.f);
            a1.x = fmaxf(a1.x * sc.x + sh.x, 0.f); a1.y = fmaxf(a1.y * sc.y + sh.y, 0.f);
            a1.z = fmaxf(a1.z * sc.z + sh.z, 0.f); a1.w = fmaxf(a1.w * sc.w + sh.w, 0.f);
        }
        if (q0 < p1) {
            acc.x += fmaxf(a0.x + b0.x, 0.f);
            acc.y += fmaxf(a0.y + b0.y, 0.f);
            acc.z += fmaxf(a0.z + b0.z, 0.f);
            acc.w += fmaxf(a0.w + b0.w, 0.f);
        }
        if (q1 < p1) {
            acc.x += fmaxf(a1.x + b1.x, 0.f);
            acc.y += fmaxf(a1.y + b1.y, 0.f);
            acc.z += fmaxf(a1.z + b1.z, 0.f);
            acc.w += fmaxf(a1.w + b1.w, 0.f);
        }
    }
    acc.x += __shfl_xor(acc.x, 32);
    acc.y += __shfl_xor(acc.y, 32);
    acc.z += __shfl_xor(acc.z, 32);
    acc.w += __shfl_xor(acc.w, 32);
    if (half == 0) {
        float s = 1.f / (float)(p1 - p0);
        acc.x *= s; acc.y *= s; acc.z *= s; acc.w *= s;
        *reinterpret_cast<float4*>(&agg[(size_t)wid * DIM + l * 4]) = acc;
    }
}

// ---------------- weight prep: frag-linear bf16 hi/lo ----------------
// frag t = ct*256 + ks*64 + lane holds W[col=ct*16+(lane&15)][k=ks*32+(lane>>4)*8+e]
__global__ void k_wprep(const float* __restrict__ W, short* __restrict__ hi,
                        short* __restrict__ lo) {
    int tt = threadIdx.x;
    int ct = blockIdx.x;
    int lane = tt & 63, ks = (tt >> 6) & 3;
    int row = ct * 16 + (lane & 15);
    int k0 = ks * 32 + ((lane >> 4) << 3);
    float4 v0 = *reinterpret_cast<const float4*>(&W[(size_t)row * DIM + k0]);
    float4 v1 = *reinterpret_cast<const float4*>(&W[(size_t)row * DIM + k0 + 4]);
    s16x8 h8, l8;
    f2hl8(v0, v1, h8, l8);
    int t = ct * 256 + ks * 64 + lane;
    *reinterpret_cast<s16x8*>(&hi[(size_t)t * 8]) = h8;
    *reinterpret_cast<s16x8*>(&lo[(size_t)t * 8]) = l8;
}

// ---------------- MFMA dual GEMM: OUT = A@W1^T + bn?(B)@W2^T + bias ----------
// block: 64 nodes, 4 waves (wave w -> rows 16w..16w+15, all 128 cols)
__global__ __launch_bounds__(256) void k_gemm2(
        const float* __restrict__ A, const float* __restrict__ B,
        const short* __restrict__ fW1h, const short* __restrict__ fW1l,
        const short* __restrict__ fW2h, const short* __restrict__ fW2l,
        const float* __restrict__ bias, float* __restrict__ OUT,
        float* __restrict__ bnacc, const float* __restrict__ bnsc,
        int doBN, int bnB) {
    __shared__ char sm[65536];  // A_hi | A_lo | B_hi | B_lo, 16 KB each, swizzled
    const int A_HI = 0, A_LO = 16384, B_HI = 32768, B_LO = 49152;
    int t = threadIdx.x;
    int n0 = blockIdx.x * 64;

    // ---- stage A,B -> bf16 hi/lo in LDS (XOR swizzle: byte ^= (row&7)<<4) ----
    {
        int row = t >> 2;        // 0..63
        int kq = t & 3;          // k-quarter (32 k)
        int n = n0 + row; if (n > N_NODES - 1) n = N_NODES - 1;
        const float* ap = &A[(size_t)n * DIM + kq * 32];
        const float* bp_ = &B[(size_t)n * DIM + kq * 32];
        int sw = (row & 7) << 4;
#pragma unroll
        for (int j = 0; j < 4; ++j) {
            int koffB = kq * 64 + j * 16;
            int addr = row * 256 + (koffB ^ sw);
            float4 v0 = *reinterpret_cast<const float4*>(ap + j * 8);
            float4 v1 = *reinterpret_cast<const float4*>(ap + j * 8 + 4);
            s16x8 h8, l8;
            f2hl8(v0, v1, h8, l8);
            *reinterpret_cast<s16x8*>(sm + A_HI + addr) = h8;
            *reinterpret_cast<s16x8*>(sm + A_LO + addr) = l8;

            float4 u0 = *reinterpret_cast<const float4*>(bp_ + j * 8);
            float4 u1 = *reinterpret_cast<const float4*>(bp_ + j * 8 + 4);
            if (bnB) {
                int k = kq * 32 + j * 8;
                float4 sc0 = *reinterpret_cast<const float4*>(&bnsc[k]);
                float4 sh0 = *reinterpret_cast<const float4*>(&bnsc[DIM + k]);
                float4 sc1 = *reinterpret_cast<const float4*>(&bnsc[k + 4]);
                float4 sh1 = *reinterpret_cast<const float4*>(&bnsc[DIM + k + 4]);
                u0.x = fmaxf(u0.x * sc0.x + sh0.x, 0.f);
                u0.y = fmaxf(u0.y * sc0.y + sh0.y, 0.f);
                u0.z = fmaxf(u0.z * sc0.z + sh0.z, 0.f);
                u0.w = fmaxf(u0.w * sc0.w + sh0.w, 0.f);
                u1.x = fmaxf(u1.x * sc1.x + sh1.x, 0.f);
                u1.y = fmaxf(u1.y * sc1.y + sh1.y, 0.f);
                u1.z = fmaxf(u1.z * sc1.z + sh1.z, 0.f);
                u1.w = fmaxf(u1.w * sc1.w + sh1.w, 0.f);
            }
            s16x8 bh8, bl8;
            f2hl8(u0, u1, bh8, bl8);
            *reinterpret_cast<s16x8*>(sm + B_HI + addr) = bh8;
            *reinterpret_cast<s16x8*>(sm + B_LO + addr) = bl8;
        }
    }
    __syncthreads();

    // ---- MFMA main loop ----
    int w = t >> 6;          // wave id 0..3
    int l = t & 63;          // lane
    f32x4 acc[8];
#pragma unroll
    for (int ct = 0; ct < 8; ++ct) acc[ct] = (f32x4){0.f, 0.f, 0.f, 0.f};

    const s16x8* w1h = (const s16x8*)fW1h;
    const s16x8* w1l = (const s16x8*)fW1l;
    const s16x8* w2h = (const s16x8*)fW2h;
    const s16x8* w2l = (const s16x8*)fW2l;
    int arow = w * 16 + (l & 15);
    int asw = (arow & 7) << 4;
#pragma unroll
    for (int ks = 0; ks < 4; ++ks) {
        int koffB = ks * 64 + ((l >> 4) << 4);
        int aaddr = arow * 256 + (koffB ^ asw);
        s16x8 ah = *reinterpret_cast<const s16x8*>(sm + A_HI + aaddr);
        s16x8 al = *reinterpret_cast<const s16x8*>(sm + A_LO + aaddr);
        s16x8 bh = *reinterpret_cast<const s16x8*>(sm + B_HI + aaddr);
        s16x8 bl = *reinterpret_cast<const s16x8*>(sm + B_LO + aaddr);
        int fb = ks * 64 + l;
#pragma unroll
        for (int ct = 0; ct < 8; ++ct) {
            int fi = ct * 256 + fb;
            s16x8 wh1 = w1h[fi], wl1 = w1l[fi];
            s16x8 wh2 = w2h[fi], wl2 = w2l[fi];
            acc[ct] = MFMA_BF16(ah, wh1, acc[ct], 0, 0, 0);
            acc[ct] = MFMA_BF16(ah, wl1, acc[ct], 0, 0, 0);
            acc[ct] = MFMA_BF16(al, wh1, acc[ct], 0, 0, 0);
            acc[ct] = MFMA_BF16(bh, wh2, acc[ct], 0, 0, 0);
            acc[ct] = MFMA_BF16(bh, wl2, acc[ct], 0, 0, 0);
            acc[ct] = MFMA_BF16(bl, wh2, acc[ct], 0, 0, 0);
        }
    }

    // ---- epilogue: bias, store, BN partial stats ----
    float p1s[8], p2s[8];
    int nbase = n0 + w * 16 + ((l >> 4) << 2);
    int col0 = l & 15;
#pragma unroll
    for (int ct = 0; ct < 8; ++ct) {
        float bj = bias[ct * 16 + col0];
        float s1 = 0.f, s2 = 0.f;
#pragma unroll
        for (int r = 0; r < 4; ++r) {
            int n = nbase + r;
            float h = acc[ct][r] + bj;
            if (n < N_NODES) {
                OUT[(size_t)n * DIM + ct * 16 + col0] = h;
                s1 += h; s2 += h * h;
            }
        }
        p1s[ct] = s1; p2s[ct] = s2;
    }
    if (doBN) {
#pragma unroll
        for (int ct = 0; ct < 8; ++ct) {
            p1s[ct] += __shfl_xor(p1s[ct], 16);
            p1s[ct] += __shfl_xor(p1s[ct], 32);
            p2s[ct] += __shfl_xor(p2s[ct], 16);
            p2s[ct] += __shfl_xor(p2s[ct], 32);
        }
        __syncthreads();   // staging LDS dead; reuse for reduction
        float* red1 = (float*)sm;            // [4][128]
        float* red2 = (float*)(sm + 2048);
        if (l < 16) {
#pragma unroll
            for (int ct = 0; ct < 8; ++ct) {
                red1[w * 128 + ct * 16 + l] = p1s[ct];
                red2[w * 128 + ct * 16 + l] = p2s[ct];
            }
        }
        __syncthreads();
        if (t < 128) {
            float s1 = red1[t] + red1[128 + t] + red1[256 + t] + red1[384 + t];
            float s2 = red2[t] + red2[128 + t] + red2[256 + t] + red2[384 + t];
            atomicAdd(&bnacc[t], s1);
            atomicAdd(&bnacc[128 + t], s2);
        }
    }
}

// ---------------- BN finalize: scale/shift vector ----------------
__global__ void k_bnfinal(const float* __restrict__ bnacc, const float* __restrict__ gamma,
                          const float* __restrict__ beta, float* __restrict__ bnsc) {
    int d = threadIdx.x;
    if (d < DIM) {
        float mu = bnacc[d] / (float)N_NODES;
        float var = bnacc[128 + d] / (float)N_NODES - mu * mu;
        float rstd = rsqrtf(var + BN_EPS);
        float sc = gamma[d] * rstd;
        bnsc[d] = sc;
        bnsc[128 + d] = beta[d] - mu * sc;
    }
}

// ---------------- graph mean pool (batch is sorted), 4 slices ----------------
__global__ void k_pool(const float* __restrict__ H1, const int* __restrict__ batch,
                       float* __restrict__ gout) {
    __shared__ float red[4][128];
    int g = blockIdx.x;
    int t = threadIdx.x;
    int d = t & 127;
    int sl = t >> 7;
    int lo = 0, hi = N_NODES;
    while (lo < hi) { int m = (lo + hi) >> 1; if (batch[m] < g) lo = m + 1; else hi = m; }
    int s = lo;
    lo = 0; hi = N_NODES;
    while (lo < hi) { int m = (lo + hi) >> 1; if (batch[m] < g + 1) lo = m + 1; else hi = m; }
    int e = lo;
    float sum = 0.f;
    for (int n = s + sl; n < e; n += 4) sum += H1[(size_t)n * DIM + d];
    red[sl][d] = sum;
    __syncthreads();
    if (t < 128) {
        float tot = red[0][d] + red[1][d] + red[2][d] + red[3][d];
        gout[g * DIM + d] = tot / (float)max(e - s, 1);
    }
}

// ---------------- MFMA projection: OUT = relu(H1) @ Wp^T + bp ----------------
__global__ __launch_bounds__(256) void k_proj(
        const float* __restrict__ H1, const short* __restrict__ fWph,
        const short* __restrict__ fWpl, const float* __restrict__ bp,
        float* __restrict__ OUT) {
    __shared__ char sm[32768];  // A_hi | A_lo
    const int A_HI = 0, A_LO = 16384;
    int t = threadIdx.x;
    int n0 = blockIdx.x * 64;
    {
        int row = t >> 2;
        int kq = t & 3;
        int n = n0 + row; if (n > N_NODES - 1) n = N_NODES - 1;
        const float* ap = &H1[(size_t)n * DIM + kq * 32];
        int sw = (row & 7) << 4;
#pragma unroll
        for (int j = 0; j < 4; ++j) {
            int koffB = kq * 64 + j * 16;
            int addr = row * 256 + (koffB ^ sw);
            float4 v0 = *reinterpret_cast<const float4*>(ap + j * 8);
            float4 v1 = *reinterpret_cast<const float4*>(ap + j * 8 + 4);
            v0.x = fmaxf(v0.x, 0.f); v0.y = fmaxf(v0.y, 0.f);
            v0.z = fmaxf(v0.z, 0.f); v0.w = fmaxf(v0.w, 0.f);
            v1.x = fmaxf(v1.x, 0.f); v1.y = fmaxf(v1.y, 0.f);
            v1.z = fmaxf(v1.w, 0.f) == v1.w ? v1.z : v1.z; // no-op guard removed below
            v1.z = fmaxf(v1.z, 0.f); v1.w = fmaxf(v1.w, 0.f);
            s16x8 h8, l8;
            f2hl8(v0, v1, h8, l8);
            *reinterpret_cast<s16x8*>(sm + A_HI + addr) = h8;
            *reinterpret_cast<s16x8*>(sm + A_LO + addr) = l8;
        }
    }
    __syncthreads();

    int w = t >> 6;
    int l = t & 63;
    f32x4 acc[4];
#pragma unroll
    for (int ct = 0; ct < 4; ++ct) acc[ct] = (f32x4){0.f, 0.f, 0.f, 0.f};
    const s16x8* wph = (const s16x8*)fWph;
    const s16x8* wpl = (const s16x8*)fWpl;
    int arow = w * 16 + (l & 15);
    int asw = (arow & 7) << 4;
#pragma unroll
    for (int ks = 0; ks < 4; ++ks) {
        int koffB = ks * 64 + ((l >> 4) << 4);
        int aaddr = arow * 256 + (koffB ^ asw);
        s16x8 ah = *reinterpret_cast<const s16x8*>(sm + A_HI + aaddr);
        s16x8 al = *reinterpret_cast<const s16x8*>(sm + A_LO + aaddr);
        int fb = ks * 64 + l;
#pragma unroll
        for (int ct = 0; ct < 4; ++ct) {
            int fi = ct * 256 + fb;
            s16x8 wh = wph[fi], wl = wpl[fi];
            acc[ct] = MFMA_BF16(ah, wh, acc[ct], 0, 0, 0);
            acc[ct] = MFMA_BF16(ah, wl, acc[ct], 0, 0, 0);
            acc[ct] = MFMA_BF16(al, wh, acc[ct], 0, 0, 0);
        }
    }
    int nbase = n0 + w * 16 + ((l >> 4) << 2);
    int col0 = l & 15;
#pragma unroll
    for (int ct = 0; ct < 4; ++ct) {
        float bj = bp[ct * 16 + col0];
#pragma unroll
        for (int r = 0; r < 4; ++r) {
            int n = nbase + r;
            if (n < N_NODES)
                OUT[(size_t)n * NCLS + ct * 16 + col0] = acc[ct][r] + bj;
        }
    }
}

extern "C" void kernel_launch(void* const* d_in, const int* in_sizes, int n_in,
                              void* d_out, int out_size, void* d_ws, size_t ws_size,
                              hipStream_t stream) {
    (void)in_sizes; (void)n_in; (void)out_size; (void)ws_size;
    const float* x     = (const float*)d_in[0];
    const float* xe    = (const float*)d_in[1];
    const int*   eidx  = (const int*)d_in[2];
    const int*   batch = (const int*)d_in[3];
    const float* Wl0   = (const float*)d_in[4];
    const float* bl0   = (const float*)d_in[5];
    const float* Wr0   = (const float*)d_in[6];
    const float* Wl1   = (const float*)d_in[7];
    const float* bl1   = (const float*)d_in[8];
    const float* Wr1   = (const float*)d_in[9];
    const float* gamma0 = (const float*)d_in[10];
    const float* beta0  = (const float*)d_in[11];
    const float* Wp    = (const float*)d_in[12];
    const float* bp    = (const float*)d_in[13];
    const int* srcp = eidx;
    const int* dstp = eidx + N_EDGES;

    char* ws = (char*)d_ws;
    size_t off = 0;
    auto carve = [&](size_t bytes) {
        void* p = ws + off;
        off = (off + bytes + 255) & ~(size_t)255;
        return p;
    };
    int*   cnt    = (int*)carve((size_t)N_NODES * 4);
    int*   rowptr = (int*)carve((size_t)(N_NODES + 1) * 4);
    int*   wcur   = (int*)carve((size_t)N_NODES * 4);
    int*   bsums  = (int*)carve(128 * 4);
    float* bnacc  = (float*)carve(256 * 4);
    float* bnsc   = (float*)carve(256 * 4);
    int2*  esort  = (int2*)carve((size_t)N_EDGES * 8);
    float* AGG    = (float*)carve((size_t)N_NODES * DIM * 4);
    float* H      = (float*)carve((size_t)N_NODES * DIM * 4);
    float* H1     = (float*)carve((size_t)N_NODES * DIM * 4);
    // frag-linear bf16 weights (hi/lo): D*D mats = 16384 shorts each
    short* fWl0h = (short*)carve(16384 * 2);
    short* fWl0l = (short*)carve(16384 * 2);
    short* fWr0h = (short*)carve(16384 * 2);
    short* fWr0l = (short*)carve(16384 * 2);
    short* fWl1h = (short*)carve(16384 * 2);
    short* fWl1l = (short*)carve(16384 * 2);
    short* fWr1h = (short*)carve(16384 * 2);
    short* fWr1l = (short*)carve(16384 * 2);
    short* fWph  = (short*)carve(8192 * 2);
    short* fWpl  = (short*)carve(8192 * 2);

    float* out_h = (float*)d_out;
    float* out_g = out_h + (size_t)N_NODES * NCLS;

    hipMemsetAsync(cnt, 0, (size_t)N_NODES * 4, stream);
    hipMemsetAsync(bnacc, 0, 256 * 4, stream);

    // weight prep (cheap, deterministic each call)
    k_wprep<<<8, 256, 0, stream>>>(Wl0, fWl0h, fWl0l);
    k_wprep<<<8, 256, 0, stream>>>(Wr0, fWr0h, fWr0l);
    k_wprep<<<8, 256, 0, stream>>>(Wl1, fWl1h, fWl1l);
    k_wprep<<<8, 256, 0, stream>>>(Wr1, fWr1h, fWr1l);
    k_wprep<<<4, 256, 0, stream>>>(Wp, fWph, fWpl);

    int nb = (N_NODES + 1023) / 1024;  // 98
    k_hist<<<(N_EDGES + 255) / 256, 256, 0, stream>>>(dstp, cnt);
    k_scan1<<<nb, 1024, 0, stream>>>(cnt, rowptr, bsums);
    k_scan2<<<1, 128, 0, stream>>>(bsums, nb);
    k_scan3<<<nb, 1024, 0, stream>>>(rowptr, bsums, wcur);
    k_scatter<<<(N_EDGES + 255) / 256, 256, 0, stream>>>(srcp, dstp, wcur, esort);

    int gblocks = (N_NODES + 63) / 64;  // 1563

    // layer 0
    k_agg<<<(N_NODES * 64 + 255) / 256, 256, 0, stream>>>(x, xe, rowptr, esort, AGG,
                                                          bnsc, 0);
    k_gemm2<<<gblocks, 256, 0, stream>>>(AGG, x, fWl0h, fWl0l, fWr0h, fWr0l,
                                         bl0, H, bnacc, bnsc, 1, 0);
    k_bnfinal<<<1, 128, 0, stream>>>(bnacc, gamma0, beta0, bnsc);

    // layer 1 (BN fused into consumers)
    k_agg<<<(N_NODES * 64 + 255) / 256, 256, 0, stream>>>(H, xe, rowptr, esort, AGG,
                                                          bnsc, 1);
    k_gemm2<<<gblocks, 256, 0, stream>>>(AGG, H, fWl1h, fWl1l, fWr1h, fWr1l,
                                         bl1, H1, bnacc, bnsc, 0, 1);

    // readout
    k_pool<<<NG, 512, 0, stream>>>(H1, batch, out_g);
    k_proj<<<gblocks, 256, 0, stream>>>(H1, fWph, fWpl, bp, out_h);
}

// Round 5
// 889.573 us; speedup vs baseline: 2.1563x; 1.1461x over previous
//
#include <hip/hip_runtime.h>

#define N_NODES 100000
#define N_EDGES 1600000
#define DIM 128
#define NCLS 64
#define NG 128
#define BN_EPS 1e-5f

typedef __attribute__((ext_vector_type(8))) short s16x8;
typedef __attribute__((ext_vector_type(4))) float f32x4;
#define MFMA_BF16 __builtin_amdgcn_mfma_f32_16x16x32_bf16

// split 8 f32 into bf16 hi + bf16 lo (truncation; dropped lo*lo term ~2^-18 rel)
__device__ __forceinline__ void f2hl8(float4 v0, float4 v1, s16x8& h8, s16x8& l8) {
    float vv[8] = {v0.x, v0.y, v0.z, v0.w, v1.x, v1.y, v1.z, v1.w};
#pragma unroll
    for (int i = 0; i < 8; ++i) {
        unsigned u = __float_as_uint(vv[i]);
        short h = (short)(u >> 16);
        float r = vv[i] - __uint_as_float(u & 0xFFFF0000u);
        short l = (short)(__float_as_uint(r) >> 16);
        h8[i] = h;
        l8[i] = l;
    }
}

__device__ __forceinline__ float4 relu4(float4 v) {
    v.x = fmaxf(v.x, 0.f); v.y = fmaxf(v.y, 0.f);
    v.z = fmaxf(v.z, 0.f); v.w = fmaxf(v.w, 0.f);
    return v;
}

// ---------------- degree histogram ----------------
__global__ void k_hist(const int* __restrict__ dst, int* __restrict__ cnt) {
    int e = blockIdx.x * 256 + threadIdx.x;
    if (e < N_EDGES) atomicAdd(&cnt[dst[e]], 1);
}

// ---------------- exclusive scan (3 kernels) ----------------
__global__ void k_scan1(const int* __restrict__ cnt, int* __restrict__ rowptr,
                        int* __restrict__ bsums) {
    __shared__ int sd[1024];
    int tid = threadIdx.x;
    int i = blockIdx.x * 1024 + tid;
    int v = (i < N_NODES) ? cnt[i] : 0;
    sd[tid] = v;
    __syncthreads();
    for (int off = 1; off < 1024; off <<= 1) {
        int t2 = (tid >= off) ? sd[tid - off] : 0;
        __syncthreads();
        sd[tid] += t2;
        __syncthreads();
    }
    if (i < N_NODES) rowptr[i] = sd[tid] - v;
    if (tid == 1023) bsums[blockIdx.x] = sd[tid];
}

__global__ void k_scan2(int* __restrict__ bsums, int nb) {
    __shared__ int sd[128];
    int t = threadIdx.x;
    int v = (t < nb) ? bsums[t] : 0;
    sd[t] = v;
    __syncthreads();
    for (int off = 1; off < 128; off <<= 1) {
        int u = (t >= off) ? sd[t - off] : 0;
        __syncthreads();
        sd[t] += u;
        __syncthreads();
    }
    if (t < nb) bsums[t] = sd[t] - v;
}

__global__ void k_scan3(int* __restrict__ rowptr, const int* __restrict__ bsums,
                        int* __restrict__ wcur) {
    int i = blockIdx.x * 1024 + threadIdx.x;
    if (i < N_NODES) {
        int v = rowptr[i] + bsums[blockIdx.x];
        rowptr[i] = v;
        wcur[i] = v;
    }
    if (i == N_NODES - 1) rowptr[N_NODES] = N_EDGES;
}

// ---------------- bucket edges by dst ----------------
__global__ void k_scatter(const int* __restrict__ src, const int* __restrict__ dst,
                          int* __restrict__ wcur, int2* __restrict__ esort) {
    int e = blockIdx.x * 256 + threadIdx.x;
    if (e < N_EDGES) {
        int d = dst[e];
        int p = atomicAdd(&wcur[d], 1);
        esort[p] = make_int2(e, src[e]);
    }
}

// ---------------- gather-aggregate: one wave/node, 4 edges/half-wave in flight
__global__ __launch_bounds__(256) void k_agg(
        const float* __restrict__ F, const float* __restrict__ xe,
        const int* __restrict__ rowptr, const int2* __restrict__ esort,
        float* __restrict__ agg, const float* __restrict__ bnsc, int applyBN) {
    int wid = (blockIdx.x * blockDim.x + threadIdx.x) >> 6;
    int lane = threadIdx.x & 63;
    if (wid >= N_NODES) return;
    int half = lane >> 5;
    int l = lane & 31;
    int p0 = rowptr[wid], p1 = rowptr[wid + 1];
    if (p0 == p1) {
        if (half == 0) {
            float4 z = make_float4(0.f, 0.f, 0.f, 0.f);
            *reinterpret_cast<float4*>(&agg[(size_t)wid * DIM + l * 4]) = z;
        }
        return;
    }
    float4 sc, sh;
    if (applyBN) {
        sc = *reinterpret_cast<const float4*>(&bnsc[l * 4]);
        sh = *reinterpret_cast<const float4*>(&bnsc[DIM + l * 4]);
    }
    float4 acc = make_float4(0.f, 0.f, 0.f, 0.f);
    for (int p = p0; p < p1; p += 8) {
        int q0 = p + half;
        int q1 = p + 2 + half;
        int q2 = p + 4 + half;
        int q3 = p + 6 + half;
        int2 e0 = esort[min(q0, p1 - 1)];
        int2 e1 = esort[min(q1, p1 - 1)];
        int2 e2 = esort[min(q2, p1 - 1)];
        int2 e3 = esort[min(q3, p1 - 1)];
        float4 a0 = *reinterpret_cast<const float4*>(&F[(size_t)e0.y * DIM + l * 4]);
        float4 b0 = *reinterpret_cast<const float4*>(&xe[(size_t)e0.x * DIM + l * 4]);
        float4 a1 = *reinterpret_cast<const float4*>(&F[(size_t)e1.y * DIM + l * 4]);
        float4 b1 = *reinterpret_cast<const float4*>(&xe[(size_t)e1.x * DIM + l * 4]);
        float4 a2 = *reinterpret_cast<const float4*>(&F[(size_t)e2.y * DIM + l * 4]);
        float4 b2 = *reinterpret_cast<const float4*>(&xe[(size_t)e2.x * DIM + l * 4]);
        float4 a3 = *reinterpret_cast<const float4*>(&F[(size_t)e3.y * DIM + l * 4]);
        float4 b3 = *reinterpret_cast<const float4*>(&xe[(size_t)e3.x * DIM + l * 4]);
        if (applyBN) {
            a0.x = fmaxf(a0.x * sc.x + sh.x, 0.f); a0.y = fmaxf(a0.y * sc.y + sh.y, 0.f);
            a0.z = fmaxf(a0.z * sc.z + sh.z, 0.f); a0.w = fmaxf(a0.w * sc.w + sh.w, 0.f);
            a1.x = fmaxf(a1.x * sc.x + sh.x, 0.f); a1.y = fmaxf(a1.y * sc.y + sh.y, 0.f);
            a1.z = fmaxf(a1.z * sc.z + sh.z, 0.f); a1.w = fmaxf(a1.w * sc.w + sh.w, 0.f);
            a2.x = fmaxf(a2.x * sc.x + sh.x, 0.f); a2.y = fmaxf(a2.y * sc.y + sh.y, 0.f);
            a2.z = fmaxf(a2.z * sc.z + sh.z, 0.f); a2.w = fmaxf(a2.w * sc.w + sh.w, 0.f);
            a3.x = fmaxf(a3.x * sc.x + sh.x, 0.f); a3.y = fmaxf(a3.y * sc.y + sh.y, 0.f);
            a3.z = fmaxf(a3.z * sc.z + sh.z, 0.f); a3.w = fmaxf(a3.w * sc.w + sh.w, 0.f);
        }
        if (q0 < p1) {
            acc.x += fmaxf(a0.x + b0.x, 0.f); acc.y += fmaxf(a0.y + b0.y, 0.f);
            acc.z += fmaxf(a0.z + b0.z, 0.f); acc.w += fmaxf(a0.w + b0.w, 0.f);
        }
        if (q1 < p1) {
            acc.x += fmaxf(a1.x + b1.x, 0.f); acc.y += fmaxf(a1.y + b1.y, 0.f);
            acc.z += fmaxf(a1.z + b1.z, 0.f); acc.w += fmaxf(a1.w + b1.w, 0.f);
        }
        if (q2 < p1) {
            acc.x += fmaxf(a2.x + b2.x, 0.f); acc.y += fmaxf(a2.y + b2.y, 0.f);
            acc.z += fmaxf(a2.z + b2.z, 0.f); acc.w += fmaxf(a2.w + b2.w, 0.f);
        }
        if (q3 < p1) {
            acc.x += fmaxf(a3.x + b3.x, 0.f); acc.y += fmaxf(a3.y + b3.y, 0.f);
            acc.z += fmaxf(a3.z + b3.z, 0.f); acc.w += fmaxf(a3.w + b3.w, 0.f);
        }
    }
    acc.x += __shfl_xor(acc.x, 32);
    acc.y += __shfl_xor(acc.y, 32);
    acc.z += __shfl_xor(acc.z, 32);
    acc.w += __shfl_xor(acc.w, 32);
    if (half == 0) {
        float s = 1.f / (float)(p1 - p0);
        acc.x *= s; acc.y *= s; acc.z *= s; acc.w *= s;
        *reinterpret_cast<float4*>(&agg[(size_t)wid * DIM + l * 4]) = acc;
    }
}

// ---------------- weight prep (ALL matrices in one launch) ----------------
// frag t = ct*256 + ks*64 + lane holds W[col=ct*16+(lane&15)][k=ks*32+(lane>>4)*8+e]
__global__ void k_wprep_all(const float* __restrict__ Wl0, const float* __restrict__ Wr0,
                            const float* __restrict__ Wl1, const float* __restrict__ Wr1,
                            const float* __restrict__ Wp,
                            short* __restrict__ fWl0h, short* __restrict__ fWl0l,
                            short* __restrict__ fWr0h, short* __restrict__ fWr0l,
                            short* __restrict__ fWl1h, short* __restrict__ fWl1l,
                            short* __restrict__ fWr1h, short* __restrict__ fWr1l,
                            short* __restrict__ fWph, short* __restrict__ fWpl) {
    int b = blockIdx.x;          // 0..35
    const float* W; short* hi; short* lo; int ct;
    if (b < 8)       { W = Wl0; hi = fWl0h; lo = fWl0l; ct = b; }
    else if (b < 16) { W = Wr0; hi = fWr0h; lo = fWr0l; ct = b - 8; }
    else if (b < 24) { W = Wl1; hi = fWl1h; lo = fWl1l; ct = b - 16; }
    else if (b < 32) { W = Wr1; hi = fWr1h; lo = fWr1l; ct = b - 24; }
    else             { W = Wp;  hi = fWph;  lo = fWpl;  ct = b - 32; }
    int tt = threadIdx.x;
    int lane = tt & 63, ks = (tt >> 6) & 3;
    int row = ct * 16 + (lane & 15);
    int k0 = ks * 32 + ((lane >> 4) << 3);
    float4 v0 = *reinterpret_cast<const float4*>(&W[(size_t)row * DIM + k0]);
    float4 v1 = *reinterpret_cast<const float4*>(&W[(size_t)row * DIM + k0 + 4]);
    s16x8 h8, l8;
    f2hl8(v0, v1, h8, l8);
    int t = ct * 256 + ks * 64 + lane;
    *reinterpret_cast<s16x8*>(&hi[(size_t)t * 8]) = h8;
    *reinterpret_cast<s16x8*>(&lo[(size_t)t * 8]) = l8;
}

// ---------------- MFMA dual GEMM (no LDS staging, 2 strips/wave) ------------
// block = 128 nodes, 4 waves; wave w: rows [n0+16w, +16) and [n0+64+16w, +16)
__global__ __launch_bounds__(256) void k_gemm2(
        const float* __restrict__ A, const float* __restrict__ B,
        const short* __restrict__ fW1h, const short* __restrict__ fW1l,
        const short* __restrict__ fW2h, const short* __restrict__ fW2l,
        const float* __restrict__ bias, float* __restrict__ OUT,
        float* __restrict__ bnacc, const float* __restrict__ bnsc,
        int doBN, int bnB) {
    int t = threadIdx.x, w = t >> 6, l = t & 63;
    int n0 = blockIdx.x * 128;
    int r = l & 15, kh = l >> 4;
    int row0 = n0 + w * 16 + r;
    int row1 = row0 + 64;
    int n_0 = min(row0, N_NODES - 1);
    int n_1 = min(row1, N_NODES - 1);

    f32x4 acc0[8], acc1[8];
#pragma unroll
    for (int ct = 0; ct < 8; ++ct) {
        acc0[ct] = (f32x4){0.f, 0.f, 0.f, 0.f};
        acc1[ct] = (f32x4){0.f, 0.f, 0.f, 0.f};
    }
    const s16x8* w1h = (const s16x8*)fW1h;
    const s16x8* w1l = (const s16x8*)fW1l;
    const s16x8* w2h = (const s16x8*)fW2h;
    const s16x8* w2l = (const s16x8*)fW2l;

#pragma unroll
    for (int ks = 0; ks < 4; ++ks) {
        int kb = ks * 32 + kh * 8;
        // strip 0
        float4 va0 = *reinterpret_cast<const float4*>(&A[(size_t)n_0 * DIM + kb]);
        float4 va1 = *reinterpret_cast<const float4*>(&A[(size_t)n_0 * DIM + kb + 4]);
        float4 vb0 = *reinterpret_cast<const float4*>(&B[(size_t)n_0 * DIM + kb]);
        float4 vb1 = *reinterpret_cast<const float4*>(&B[(size_t)n_0 * DIM + kb + 4]);
        // strip 1
        float4 wa0 = *reinterpret_cast<const float4*>(&A[(size_t)n_1 * DIM + kb]);
        float4 wa1 = *reinterpret_cast<const float4*>(&A[(size_t)n_1 * DIM + kb + 4]);
        float4 wb0 = *reinterpret_cast<const float4*>(&B[(size_t)n_1 * DIM + kb]);
        float4 wb1 = *reinterpret_cast<const float4*>(&B[(size_t)n_1 * DIM + kb + 4]);
        if (bnB) {
            float4 sc0 = *reinterpret_cast<const float4*>(&bnsc[kb]);
            float4 sh0 = *reinterpret_cast<const float4*>(&bnsc[DIM + kb]);
            float4 sc1 = *reinterpret_cast<const float4*>(&bnsc[kb + 4]);
            float4 sh1 = *reinterpret_cast<const float4*>(&bnsc[DIM + kb + 4]);
            vb0.x = fmaxf(vb0.x * sc0.x + sh0.x, 0.f);
            vb0.y = fmaxf(vb0.y * sc0.y + sh0.y, 0.f);
            vb0.z = fmaxf(vb0.z * sc0.z + sh0.z, 0.f);
            vb0.w = fmaxf(vb0.w * sc0.w + sh0.w, 0.f);
            vb1.x = fmaxf(vb1.x * sc1.x + sh1.x, 0.f);
            vb1.y = fmaxf(vb1.y * sc1.y + sh1.y, 0.f);
            vb1.z = fmaxf(vb1.z * sc1.z + sh1.z, 0.f);
            vb1.w = fmaxf(vb1.w * sc1.w + sh1.w, 0.f);
            wb0.x = fmaxf(wb0.x * sc0.x + sh0.x, 0.f);
            wb0.y = fmaxf(wb0.y * sc0.y + sh0.y, 0.f);
            wb0.z = fmaxf(wb0.z * sc0.z + sh0.z, 0.f);
            wb0.w = fmaxf(wb0.w * sc0.w + sh0.w, 0.f);
            wb1.x = fmaxf(wb1.x * sc1.x + sh1.x, 0.f);
            wb1.y = fmaxf(wb1.y * sc1.y + sh1.y, 0.f);
            wb1.z = fmaxf(wb1.z * sc1.z + sh1.z, 0.f);
            wb1.w = fmaxf(wb1.w * sc1.w + sh1.w, 0.f);
        }
        s16x8 a0h, a0l, b0h, b0l, a1h, a1l, b1h, b1l;
        f2hl8(va0, va1, a0h, a0l);
        f2hl8(vb0, vb1, b0h, b0l);
        f2hl8(wa0, wa1, a1h, a1l);
        f2hl8(wb0, wb1, b1h, b1l);
        int fb = ks * 64 + l;
#pragma unroll
        for (int ct = 0; ct < 8; ++ct) {
            int fi = ct * 256 + fb;
            s16x8 wh1 = w1h[fi], wl1 = w1l[fi];
            s16x8 wh2 = w2h[fi], wl2 = w2l[fi];
            acc0[ct] = MFMA_BF16(a0h, wh1, acc0[ct], 0, 0, 0);
            acc0[ct] = MFMA_BF16(a0h, wl1, acc0[ct], 0, 0, 0);
            acc0[ct] = MFMA_BF16(a0l, wh1, acc0[ct], 0, 0, 0);
            acc0[ct] = MFMA_BF16(b0h, wh2, acc0[ct], 0, 0, 0);
            acc0[ct] = MFMA_BF16(b0h, wl2, acc0[ct], 0, 0, 0);
            acc0[ct] = MFMA_BF16(b0l, wh2, acc0[ct], 0, 0, 0);
            acc1[ct] = MFMA_BF16(a1h, wh1, acc1[ct], 0, 0, 0);
            acc1[ct] = MFMA_BF16(a1h, wl1, acc1[ct], 0, 0, 0);
            acc1[ct] = MFMA_BF16(a1l, wh1, acc1[ct], 0, 0, 0);
            acc1[ct] = MFMA_BF16(b1h, wh2, acc1[ct], 0, 0, 0);
            acc1[ct] = MFMA_BF16(b1h, wl2, acc1[ct], 0, 0, 0);
            acc1[ct] = MFMA_BF16(b1l, wh2, acc1[ct], 0, 0, 0);
        }
    }

    // ---- epilogue: bias, store, BN partial stats ----
    float p1s[8], p2s[8];
    int col0 = l & 15;
    int nb0 = n0 + w * 16 + (kh << 2);
    int nb1 = nb0 + 64;
#pragma unroll
    for (int ct = 0; ct < 8; ++ct) {
        float bj = bias[ct * 16 + col0];
        float s1 = 0.f, s2 = 0.f;
#pragma unroll
        for (int rr = 0; rr < 4; ++rr) {
            int n = nb0 + rr;
            float h = acc0[ct][rr] + bj;
            if (n < N_NODES) {
                OUT[(size_t)n * DIM + ct * 16 + col0] = h;
                s1 += h; s2 += h * h;
            }
            n = nb1 + rr;
            h = acc1[ct][rr] + bj;
            if (n < N_NODES) {
                OUT[(size_t)n * DIM + ct * 16 + col0] = h;
                s1 += h; s2 += h * h;
            }
        }
        p1s[ct] = s1; p2s[ct] = s2;
    }
    if (doBN) {
        __shared__ float red1[512];
        __shared__ float red2[512];
#pragma unroll
        for (int ct = 0; ct < 8; ++ct) {
            p1s[ct] += __shfl_xor(p1s[ct], 16);
            p1s[ct] += __shfl_xor(p1s[ct], 32);
            p2s[ct] += __shfl_xor(p2s[ct], 16);
            p2s[ct] += __shfl_xor(p2s[ct], 32);
        }
        if (l < 16) {
#pragma unroll
            for (int ct = 0; ct < 8; ++ct) {
                red1[w * 128 + ct * 16 + l] = p1s[ct];
                red2[w * 128 + ct * 16 + l] = p2s[ct];
            }
        }
        __syncthreads();
        if (t < 128) {
            float s1 = red1[t] + red1[128 + t] + red1[256 + t] + red1[384 + t];
            float s2 = red2[t] + red2[128 + t] + red2[256 + t] + red2[384 + t];
            atomicAdd(&bnacc[t], s1);
            atomicAdd(&bnacc[128 + t], s2);
        }
    }
}

// ---------------- BN finalize: scale/shift vector ----------------
__global__ void k_bnfinal(const float* __restrict__ bnacc, const float* __restrict__ gamma,
                          const float* __restrict__ beta, float* __restrict__ bnsc) {
    int d = threadIdx.x;
    if (d < DIM) {
        float mu = bnacc[d] / (float)N_NODES;
        float var = bnacc[128 + d] / (float)N_NODES - mu * mu;
        float rstd = rsqrtf(var + BN_EPS);
        float sc = gamma[d] * rstd;
        bnsc[d] = sc;
        bnsc[128 + d] = beta[d] - mu * sc;
    }
}

// ---------------- graph mean pool (batch is sorted), 4 slices ----------------
__global__ void k_pool(const float* __restrict__ H1, const int* __restrict__ batch,
                       float* __restrict__ gout) {
    __shared__ float red[4][128];
    int g = blockIdx.x;
    int t = threadIdx.x;
    int d = t & 127;
    int sl = t >> 7;
    int lo = 0, hi = N_NODES;
    while (lo < hi) { int m = (lo + hi) >> 1; if (batch[m] < g) lo = m + 1; else hi = m; }
    int s = lo;
    lo = 0; hi = N_NODES;
    while (lo < hi) { int m = (lo + hi) >> 1; if (batch[m] < g + 1) lo = m + 1; else hi = m; }
    int e = lo;
    float sum = 0.f;
    for (int n = s + sl; n < e; n += 4) sum += H1[(size_t)n * DIM + d];
    red[sl][d] = sum;
    __syncthreads();
    if (t < 128) {
        float tot = red[0][d] + red[1][d] + red[2][d] + red[3][d];
        gout[g * DIM + d] = tot / (float)max(e - s, 1);
    }
}

// ---------------- MFMA projection (no LDS, 2 strips/wave) --------------------
__global__ __launch_bounds__(256) void k_proj(
        const float* __restrict__ H1, const short* __restrict__ fWph,
        const short* __restrict__ fWpl, const float* __restrict__ bp,
        float* __restrict__ OUT) {
    int t = threadIdx.x, w = t >> 6, l = t & 63;
    int n0 = blockIdx.x * 128;
    int r = l & 15, kh = l >> 4;
    int row0 = n0 + w * 16 + r;
    int row1 = row0 + 64;
    int n_0 = min(row0, N_NODES - 1);
    int n_1 = min(row1, N_NODES - 1);
    f32x4 acc0[4], acc1[4];
#pragma unroll
    for (int ct = 0; ct < 4; ++ct) {
        acc0[ct] = (f32x4){0.f, 0.f, 0.f, 0.f};
        acc1[ct] = (f32x4){0.f, 0.f, 0.f, 0.f};
    }
    const s16x8* wph = (const s16x8*)fWph;
    const s16x8* wpl = (const s16x8*)fWpl;
#pragma unroll
    for (int ks = 0; ks < 4; ++ks) {
        int kb = ks * 32 + kh * 8;
        float4 va0 = relu4(*reinterpret_cast<const float4*>(&H1[(size_t)n_0 * DIM + kb]));
        float4 va1 = relu4(*reinterpret_cast<const float4*>(&H1[(size_t)n_0 * DIM + kb + 4]));
        float4 wa0 = relu4(*reinterpret_cast<const float4*>(&H1[(size_t)n_1 * DIM + kb]));
        float4 wa1 = relu4(*reinterpret_cast<const float4*>(&H1[(size_t)n_1 * DIM + kb + 4]));
        s16x8 a0h, a0l, a1h, a1l;
        f2hl8(va0, va1, a0h, a0l);
        f2hl8(wa0, wa1, a1h, a1l);
        int fb = ks * 64 + l;
#pragma unroll
        for (int ct = 0; ct < 4; ++ct) {
            int fi = ct * 256 + fb;
            s16x8 wh = wph[fi], wl = wpl[fi];
            acc0[ct] = MFMA_BF16(a0h, wh, acc0[ct], 0, 0, 0);
            acc0[ct] = MFMA_BF16(a0h, wl, acc0[ct], 0, 0, 0);
            acc0[ct] = MFMA_BF16(a0l, wh, acc0[ct], 0, 0, 0);
            acc1[ct] = MFMA_BF16(a1h, wh, acc1[ct], 0, 0, 0);
            acc1[ct] = MFMA_BF16(a1h, wl, acc1[ct], 0, 0, 0);
            acc1[ct] = MFMA_BF16(a1l, wh, acc1[ct], 0, 0, 0);
        }
    }
    int col0 = l & 15;
    int nb0 = n0 + w * 16 + (kh << 2);
    int nb1 = nb0 + 64;
#pragma unroll
    for (int ct = 0; ct < 4; ++ct) {
        float bj = bp[ct * 16 + col0];
#pragma unroll
        for (int rr = 0; rr < 4; ++rr) {
            int n = nb0 + rr;
            if (n < N_NODES)
                OUT[(size_t)n * NCLS + ct * 16 + col0] = acc0[ct][rr] + bj;
            n = nb1 + rr;
            if (n < N_NODES)
                OUT[(size_t)n * NCLS + ct * 16 + col0] = acc1[ct][rr] + bj;
        }
    }
}

extern "C" void kernel_launch(void* const* d_in, const int* in_sizes, int n_in,
                              void* d_out, int out_size, void* d_ws, size_t ws_size,
                              hipStream_t stream) {
    (void)in_sizes; (void)n_in; (void)out_size; (void)ws_size;
    const float* x     = (const float*)d_in[0];
    const float* xe    = (const float*)d_in[1];
    const int*   eidx  = (const int*)d_in[2];
    const int*   batch = (const int*)d_in[3];
    const float* Wl0   = (const float*)d_in[4];
    const float* bl0   = (const float*)d_in[5];
    const float* Wr0   = (const float*)d_in[6];
    const float* Wl1   = (const float*)d_in[7];
    const float* bl1   = (const float*)d_in[8];
    const float* Wr1   = (const float*)d_in[9];
    const float* gamma0 = (const float*)d_in[10];
    const float* beta0  = (const float*)d_in[11];
    const float* Wp    = (const float*)d_in[12];
    const float* bp    = (const float*)d_in[13];
    const int* srcp = eidx;
    const int* dstp = eidx + N_EDGES;

    char* ws = (char*)d_ws;
    size_t off = 0;
    auto carve = [&](size_t bytes) {
        void* p = ws + off;
        off = (off + bytes + 255) & ~(size_t)255;
        return p;
    };
    int*   cnt    = (int*)carve((size_t)N_NODES * 4);
    int*   rowptr = (int*)carve((size_t)(N_NODES + 1) * 4);
    int*   wcur   = (int*)carve((size_t)N_NODES * 4);
    int*   bsums  = (int*)carve(128 * 4);
    float* bnacc  = (float*)carve(256 * 4);
    float* bnsc   = (float*)carve(256 * 4);
    int2*  esort  = (int2*)carve((size_t)N_EDGES * 8);
    float* AGG    = (float*)carve((size_t)N_NODES * DIM * 4);
    float* H      = (float*)carve((size_t)N_NODES * DIM * 4);
    float* H1     = (float*)carve((size_t)N_NODES * DIM * 4);
    short* fWl0h = (short*)carve(16384 * 2);
    short* fWl0l = (short*)carve(16384 * 2);
    short* fWr0h = (short*)carve(16384 * 2);
    short* fWr0l = (short*)carve(16384 * 2);
    short* fWl1h = (short*)carve(16384 * 2);
    short* fWl1l = (short*)carve(16384 * 2);
    short* fWr1h = (short*)carve(16384 * 2);
    short* fWr1l = (short*)carve(16384 * 2);
    short* fWph  = (short*)carve(8192 * 2);
    short* fWpl  = (short*)carve(8192 * 2);

    float* out_h = (float*)d_out;
    float* out_g = out_h + (size_t)N_NODES * NCLS;

    hipMemsetAsync(cnt, 0, (size_t)N_NODES * 4, stream);
    hipMemsetAsync(bnacc, 0, 256 * 4, stream);

    k_wprep_all<<<36, 256, 0, stream>>>(Wl0, Wr0, Wl1, Wr1, Wp,
                                        fWl0h, fWl0l, fWr0h, fWr0l,
                                        fWl1h, fWl1l, fWr1h, fWr1l,
                                        fWph, fWpl);

    int nb = (N_NODES + 1023) / 1024;  // 98
    k_hist<<<(N_EDGES + 255) / 256, 256, 0, stream>>>(dstp, cnt);
    k_scan1<<<nb, 1024, 0, stream>>>(cnt, rowptr, bsums);
    k_scan2<<<1, 128, 0, stream>>>(bsums, nb);
    k_scan3<<<nb, 1024, 0, stream>>>(rowptr, bsums, wcur);
    k_scatter<<<(N_EDGES + 255) / 256, 256, 0, stream>>>(srcp, dstp, wcur, esort);

    int gblocks = (N_NODES + 127) / 128;  // 782

    // layer 0
    k_agg<<<(N_NODES * 64 + 255) / 256, 256, 0, stream>>>(x, xe, rowptr, esort, AGG,
                                                          bnsc, 0);
    k_gemm2<<<gblocks, 256, 0, stream>>>(AGG, x, fWl0h, fWl0l, fWr0h, fWr0l,
                                         bl0, H, bnacc, bnsc, 1, 0);
    k_bnfinal<<<1, 128, 0, stream>>>(bnacc, gamma0, beta0, bnsc);

    // layer 1 (BN fused into consumers)
    k_agg<<<(N_NODES * 64 + 255) / 256, 256, 0, stream>>>(H, xe, rowptr, esort, AGG,
                                                          bnsc, 1);
    k_gemm2<<<gblocks, 256, 0, stream>>>(AGG, H, fWl1h, fWl1l, fWr1h, fWr1l,
                                         bl1, H1, bnacc, bnsc, 0, 1);

    // readout
    k_pool<<<NG, 512, 0, stream>>>(H1, batch, out_g);
    k_proj<<<gblocks, 256, 0, stream>>>(H1, fWph, fWpl, bp, out_h);
}